// Round 1
// baseline (61.561 us; speedup 1.0000x reference)
//
#include <hip/hip_runtime.h>

// SpanRepLayer: start / inner-maxpool / end span reps.
// B=2, NS=512, S=1024, H=128. Output (B, NS, 3H) f32.
// Masked spans -> all-zero output rows (reference multiplies by mask at the end).

#define B_  2
#define NS_ 512
#define S_  1024
#define H_  128
#define H4_ (H_ / 4)   // 32 float4s per H-vector

__global__ __launch_bounds__(256) void span_rep_kernel(
    const float4* __restrict__ tr,    // (B, S, H/4) as float4
    const int2*   __restrict__ ids,   // (B*NS) [start, end+1]
    const int*    __restrict__ masks, // (B*NS) 0/1
    float4*       __restrict__ out)   // (B*NS, 3, H/4)
{
    int i  = blockIdx.x * blockDim.x + threadIdx.x;   // [0, B*NS*H4)
    int sp = i >> 5;          // span index (B*NS)
    int h4 = i & (H4_ - 1);   // which float4 within H

    float4* o = out + (size_t)sp * (3 * H4_);

    if (masks[sp] == 0) {
        float4 z = make_float4(0.f, 0.f, 0.f, 0.f);
        o[h4]            = z;
        o[H4_ + h4]      = z;
        o[2 * H4_ + h4]  = z;
        return;
    }

    int2 se    = ids[sp];
    int  start = se.x;
    int  end   = se.y - 1;    // inclusive end
    int  b     = sp / NS_;

    const float4* base = tr + (size_t)b * S_ * H4_ + h4;

    float4 sv = base[(size_t)start * H4_];
    float4 ev = base[(size_t)end   * H4_];

    float4 iv = sv;                        // fallback when no inner region
    if (end - 1 >= start + 1) {            // has_inner
        float4 m = base[(size_t)(start + 1) * H4_];
        for (int t = start + 2; t <= end - 1; ++t) {
            float4 v = base[(size_t)t * H4_];
            m.x = fmaxf(m.x, v.x);
            m.y = fmaxf(m.y, v.y);
            m.z = fmaxf(m.z, v.z);
            m.w = fmaxf(m.w, v.w);
        }
        iv = m;
    }

    o[h4]           = sv;
    o[H4_ + h4]     = iv;
    o[2 * H4_ + h4] = ev;
}

extern "C" void kernel_launch(void* const* d_in, const int* in_sizes, int n_in,
                              void* d_out, int out_size, void* d_ws, size_t ws_size,
                              hipStream_t stream) {
    const float4* tr    = (const float4*)d_in[0];
    const int2*   ids   = (const int2*)d_in[1];
    const int*    masks = (const int*)d_in[2];
    float4*       out   = (float4*)d_out;

    const int total  = B_ * NS_ * H4_;   // 32768 threads
    const int block  = 256;
    const int grid   = (total + block - 1) / block;   // 128 blocks
    span_rep_kernel<<<grid, block, 0, stream>>>(tr, ids, masks, out);
}

// Round 2
// 58.465 us; speedup vs baseline: 1.0530x; 1.0530x over previous
//
#include <hip/hip_runtime.h>

// SpanRepLayer: start / inner-maxpool / end span reps.
// B=2, NS=512, S=1024, H=128. Output (B, NS, 3H) f32.
// Masked spans -> all-zero output rows (reference multiplies by mask at the end).
//
// R2: 512 blocks x 64 threads (2 waves/CU on all 256 CUs, was 128 blocks
// covering half the chip) + constant-trip (14) inner loop with index clamped
// to end-1 so all gather loads are independent and issue in one vmcnt batch
// (was a dynamic-trip loop = serialized ~200cyc L2-hit latency chain).

#define B_  2
#define NS_ 512
#define S_  1024
#define H_  128
#define H4_ (H_ / 4)   // 32 float4s per H-vector

__global__ __launch_bounds__(64) void span_rep_kernel(
    const float4* __restrict__ tr,    // (B, S, H/4) as float4
    const int2*   __restrict__ ids,   // (B*NS) [start, end+1]
    const int*    __restrict__ masks, // (B*NS) 0/1
    float4*       __restrict__ out)   // (B*NS, 3, H/4)
{
    int i  = blockIdx.x * 64 + threadIdx.x;   // [0, B*NS*H4)
    int sp = i >> 5;          // span index (B*NS)
    int h4 = i & (H4_ - 1);   // which float4 within H

    float4* o = out + (size_t)sp * (3 * H4_);

    if (masks[sp] == 0) {
        float4 z = make_float4(0.f, 0.f, 0.f, 0.f);
        o[h4]            = z;
        o[H4_ + h4]      = z;
        o[2 * H4_ + h4]  = z;
        return;
    }

    int2 se    = ids[sp];
    int  start = se.x;
    int  end   = se.y - 1;    // inclusive end
    int  b     = sp >> 9;     // sp / NS_

    const float4* base = tr + (size_t)b * S_ * H4_ + h4;

    float4 sv = base[(size_t)start * H4_];
    float4 ev = base[(size_t)end   * H4_];

    float4 iv = sv;                        // fallback when no inner region
    if (end - start >= 2) {                // has_inner (len >= 3)
        const int last = end - 1;          // inclusive inner end
        float4 m = base[(size_t)(start + 1) * H4_];
        #pragma unroll
        for (int t = 2; t <= 14; ++t) {    // inner count <= 14 (MAX_W=16)
            int idx = start + t;
            idx = idx > last ? last : idx; // clamp: duplicate loads don't change max
            float4 v = base[(size_t)idx * H4_];
            m.x = fmaxf(m.x, v.x);
            m.y = fmaxf(m.y, v.y);
            m.z = fmaxf(m.z, v.z);
            m.w = fmaxf(m.w, v.w);
        }
        iv = m;
    }

    o[h4]           = sv;
    o[H4_ + h4]     = iv;
    o[2 * H4_ + h4] = ev;
}

extern "C" void kernel_launch(void* const* d_in, const int* in_sizes, int n_in,
                              void* d_out, int out_size, void* d_ws, size_t ws_size,
                              hipStream_t stream) {
    const float4* tr    = (const float4*)d_in[0];
    const int2*   ids   = (const int2*)d_in[1];
    const int*    masks = (const int*)d_in[2];
    float4*       out   = (float4*)d_out;

    const int total = B_ * NS_ * H4_;           // 32768 threads
    const int block = 64;
    const int grid  = total / block;            // 512 blocks -> 2 waves/CU chip-wide
    span_rep_kernel<<<grid, block, 0, stream>>>(tr, ids, masks, out);
}

// Round 3
// 57.915 us; speedup vs baseline: 1.0630x; 1.0095x over previous
//
#include <hip/hip_runtime.h>

// SpanRepLayer: start / inner-maxpool / end span reps.
// B=2, NS=512, S=1024, H=128. Output (B, NS, 3H) f32.
//
// R3: fully branchless. masks+ids load in one vmcnt round (was masks ->
// branch -> ids = 3 serialized latency rounds), 16 always-executed clamped
// gathers in a second round, mask applied as a float multiply (matches the
// reference's `span_reps * span_masks`). No wave divergence anywhere.

#define B_  2
#define NS_ 512
#define S_  1024
#define H_  128
#define H4_ (H_ / 4)   // 32 float4s per H-vector

__global__ __launch_bounds__(64) void span_rep_kernel(
    const float4* __restrict__ tr,    // (B, S, H/4) as float4
    const int2*   __restrict__ ids,   // (B*NS) [start, end+1]
    const int*    __restrict__ masks, // (B*NS) 0/1
    float4*       __restrict__ out)   // (B*NS, 3, H/4)
{
    int i  = blockIdx.x * 64 + threadIdx.x;   // [0, B*NS*H4)
    int sp = i >> 5;          // span index (B*NS)
    int h4 = i & (H4_ - 1);   // which float4 within H

    // Round 1: both small loads issue together (independent).
    int2 se = ids[sp];
    int  mk = masks[sp];

    int start = se.x;
    int end   = se.y - 1;          // inclusive end
    int b     = sp >> 9;           // sp / NS_

    const float4* base = tr + (size_t)b * S_ * H4_ + h4;

    // Inner window [start+1, end-1]; hi clamped so indices stay valid even
    // when no inner region exists (start+1 <= S-1 always, since start <= S-17).
    int lo = start + 1;
    int hi = end - 1;
    hi = hi < lo ? lo : hi;
    bool has_inner = (end - start) >= 2;

    // Round 2: 16 independent gathers, one vmcnt batch.
    float4 sv = base[(size_t)start * H4_];
    float4 ev = base[(size_t)end   * H4_];
    float4 m  = base[(size_t)lo    * H4_];
    #pragma unroll
    for (int t = 2; t <= 14; ++t) {    // inner length <= 14 (MAX_W=16)
        int idx = start + t;
        idx = idx > hi ? hi : idx;     // duplicate loads don't change max
        float4 v = base[(size_t)idx * H4_];
        m.x = fmaxf(m.x, v.x);
        m.y = fmaxf(m.y, v.y);
        m.z = fmaxf(m.z, v.z);
        m.w = fmaxf(m.w, v.w);
    }

    float4 iv = has_inner ? m : sv;

    float f = (float)mk;               // 0.0 or 1.0
    sv.x *= f; sv.y *= f; sv.z *= f; sv.w *= f;
    iv.x *= f; iv.y *= f; iv.z *= f; iv.w *= f;
    ev.x *= f; ev.y *= f; ev.z *= f; ev.w *= f;

    float4* o = out + (size_t)sp * (3 * H4_);
    o[h4]           = sv;
    o[H4_ + h4]     = iv;
    o[2 * H4_ + h4] = ev;
}

extern "C" void kernel_launch(void* const* d_in, const int* in_sizes, int n_in,
                              void* d_out, int out_size, void* d_ws, size_t ws_size,
                              hipStream_t stream) {
    const float4* tr    = (const float4*)d_in[0];
    const int2*   ids   = (const int2*)d_in[1];
    const int*    masks = (const int*)d_in[2];
    float4*       out   = (float4*)d_out;

    const int total = B_ * NS_ * H4_;           // 32768 threads
    const int block = 64;
    const int grid  = total / block;            // 512 blocks -> 2 waves/CU chip-wide
    span_rep_kernel<<<grid, block, 0, stream>>>(tr, ids, masks, out);
}